// Round 17
// baseline (27.754 us; speedup 1.0000x reference)
//
#include <hip/hip_runtime.h>

#define NBATCH 32
#define NSEG 255
#define SIGLEN 4680       // 8 + 64 + 512 + 4096
#define PSTR 4608         // partial: S3(512) + S4(4096) floats
#define INV6 (1.0f/6.0f)
#define INV24 (1.0f/24.0f)

typedef float v2f __attribute__((ext_vector_type(2)));
typedef unsigned long long u64;

// Commutative ("moment") form of the depth-4 signature (verified R15/R16):
//   S2[ab]   = sum_k w_k,  w_k = d_k[b]*(x_k-x0)[a] + 0.5*d_k[a]*d_k[b]
//   Q_j[ab]  = d_a d_b/6  + (x_j-x0)[a] d_b/2 + S2pre_j[ab]
//   P_j[ab]  = d_a d_b/24 + (x_j-x0)[a] d_b/6 + S2pre_j[ab]/2
//   S3[abc]  = sum_j Q_j[ab] d_j[c]
//   S4[abce] = sum_j d_j[c] * ( Q_j[ab]*(xT-x_{j+1})[e] + P_j[ab]*d_j[e] )
// All S3/S4 summands independent given the scalar prefix S2pre ->
// cross-block combine is PURE ADDITION.
//
// 256 blocks = 32 batches x 8 chunks of 32 segments; 512 thr = 8 waves.
// Every block: stage full path; phase A: wave w -> 8 sub-chunk w-sums
// (4 segs each) into WSS; prefix by LDS adds; phase B: 4 segs/wave, full
// c-range; 3-round pure-add tree; wave 0 sc1-stores the 4608-float partial.
// Block cb==0 writes S1/S2 directly. Last arriver (relaxed agent flag) does
// a flat 8-way sum into out[72..4680). Fixed order => deterministic.
__global__ __launch_bounds__(512)
__attribute__((amdgpu_waves_per_eu(2, 2)))
void sig_kernel(const float* __restrict__ path, float* __restrict__ pbase,
                int* __restrict__ flags, float* __restrict__ out) {
    const int blk = blockIdx.x;
    const int n = blk >> 3, cb = blk & 7;
    const int t = threadIdx.x;
    const int w = t >> 6, l = t & 63, a = l >> 3, b = l & 7;

    __shared__ float pbuf[2048];      // path row
    __shared__ float dbuf[2048];      // d_j (j=255 -> 0 pad)
    __shared__ float r1buf[2048];     // xT - x_{j+1}
    __shared__ float WSS[64][64];     // 4-seg sub-chunk w-sums (16 KB)
    __shared__ float PB[4][36 * 128]; // add-reduce buffers (72 KB)
    __shared__ int sh_old;

    const float* prow = path + n * 2048;
    { const int i4 = t * 4; *(float4*)&pbuf[i4] = *(const float4*)&prow[i4]; }
    __syncthreads();
    {
        const int i4 = t * 4;
        if (i4 < NSEG * 8) {
            const float4 xv0 = *(const float4*)&pbuf[i4];
            const float4 xv1 = *(const float4*)&pbuf[i4 + 8];
            *(float4*)&dbuf[i4] = make_float4(xv1.x - xv0.x, xv1.y - xv0.y,
                                              xv1.z - xv0.z, xv1.w - xv0.w);
            const float4 xt = *(const float4*)&pbuf[2040 + (i4 & 4)];
            *(float4*)&r1buf[i4] = make_float4(xt.x - xv1.x, xt.y - xv1.y,
                                               xt.z - xv1.z, xt.w - xv1.w);
        } else {
            *(float4*)&dbuf[i4]  = make_float4(0.f, 0.f, 0.f, 0.f);
            *(float4*)&r1buf[i4] = make_float4(0.f, 0.f, 0.f, 0.f);
        }
    }
    __syncthreads();

    const float x0a = pbuf[a];

    // ---- phase A: wave w -> 8 sub-chunk w-sums (segs [4s, 4s+4)) ----
    #pragma unroll
    for (int s8 = 0; s8 < 8; ++s8) {
        const int s = 8 * w + s8;
        float acc = 0.f;
        #pragma unroll
        for (int k = 4 * s; k < 4 * s + 4; ++k) {
            const float da = dbuf[k * 8 + a], db = dbuf[k * 8 + b];
            const float xa = pbuf[k * 8 + a] - x0a;
            acc = fmaf(db, fmaf(0.5f, da, xa), acc);
        }
        WSS[s][l] = acc;
    }
    __syncthreads();

    // ---- S2 prefix at this wave's window (sub-chunks < 8*cb + w) ----
    float S2w = 0.f;
    const int npre = 8 * cb + w;
    for (int s = 0; s < npre; ++s) S2w += WSS[s][l];

    // ---- phase B: 4 segments, full c-range ----
    v2f C[32];           // C[c*4+eh] = S4[l][c][2eh..2eh+1] partial
    v2f S3C[4];          // S3C[ch]   = S3[l][2ch..2ch+1] partial
    #pragma unroll
    for (int j = 0; j < 32; ++j) C[j] = (v2f)0.f;
    #pragma unroll
    for (int j = 0; j < 4; ++j) S3C[j] = (v2f)0.f;

    const int j0 = cb * 32 + 4 * w;
    #pragma unroll
    for (int ss = 0; ss < 4; ++ss) {
        const int j = j0 + ss;
        const v2f dp[4] = {*(const v2f*)&dbuf[j * 8 + 0],
                           *(const v2f*)&dbuf[j * 8 + 2],
                           *(const v2f*)&dbuf[j * 8 + 4],
                           *(const v2f*)&dbuf[j * 8 + 6]};
        const v2f rp[4] = {*(const v2f*)&r1buf[j * 8 + 0],
                           *(const v2f*)&r1buf[j * 8 + 2],
                           *(const v2f*)&r1buf[j * 8 + 4],
                           *(const v2f*)&r1buf[j * 8 + 6]};
        const float da = dbuf[j * 8 + a], db = dbuf[j * 8 + b];
        const float S1a = pbuf[j * 8 + a] - x0a;
        const float dab = da * db;
        const float sdb = S1a * db;
        const float Q = fmaf(dab, INV6,  fmaf(sdb, 0.5f, S2w));
        const float P = fmaf(dab, INV24, fmaf(sdb, INV6, 0.5f * S2w));
        const v2f Qv = Q, Pv = P;
        v2f E[4];
        #pragma unroll
        for (int eh = 0; eh < 4; ++eh)
            E[eh] = __builtin_elementwise_fma(Qv, rp[eh], Pv * dp[eh]);
        const float dcs[8] = {dp[0].x, dp[0].y, dp[1].x, dp[1].y,
                              dp[2].x, dp[2].y, dp[3].x, dp[3].y};
        #pragma unroll
        for (int c = 0; c < 8; ++c) {
            const v2f dcv = dcs[c];
            #pragma unroll
            for (int eh = 0; eh < 4; ++eh)
                C[c * 4 + eh] = __builtin_elementwise_fma(dcv, E[eh], C[c * 4 + eh]);
        }
        #pragma unroll
        for (int ch = 0; ch < 4; ++ch)
            S3C[ch] = __builtin_elementwise_fma(Qv, dp[ch], S3C[ch]);
        S2w = fmaf(db, fmaf(0.5f, da, S1a), S2w);
    }

    // ---- 3-round pure-add tree; wave 0 ends with the block's sums ----
    #pragma unroll
    for (int r = 0; r < 3; ++r) {
        const int stride = 1 << r;
        const int m = (stride << 1) - 1;
        const int buf = w >> (r + 1);
        if ((w & m) == stride) {
            #pragma unroll
            for (int s = 0; s < 32; ++s) *(v2f*)&PB[buf][s * 128 + 2 * l] = C[s];
            #pragma unroll
            for (int ch = 0; ch < 4; ++ch)
                *(v2f*)&PB[buf][(32 + ch) * 128 + 2 * l] = S3C[ch];
        }
        __syncthreads();
        if ((w & m) == 0) {
            #pragma unroll
            for (int s = 0; s < 32; ++s) C[s] += *(const v2f*)&PB[buf][s * 128 + 2 * l];
            #pragma unroll
            for (int ch = 0; ch < 4; ++ch)
                S3C[ch] += *(const v2f*)&PB[buf][(32 + ch) * 128 + 2 * l];
        }
        __syncthreads();
    }

    // ---- wave 0: sc1-store partial [S3|S4]; block 0 writes S1/S2 ----
    if (w == 0) {
        float* p = pbase + (size_t)blk * PSTR;
        #pragma unroll
        for (int ch = 0; ch < 4; ++ch) {
            u64 uv; __builtin_memcpy(&uv, &S3C[ch], 8);
            __hip_atomic_store((u64*)&p[l * 8 + 2 * ch], uv,
                               __ATOMIC_RELAXED, __HIP_MEMORY_SCOPE_AGENT);
        }
        #pragma unroll
        for (int c = 0; c < 8; ++c)
            #pragma unroll
            for (int eh = 0; eh < 4; ++eh) {
                u64 uv; __builtin_memcpy(&uv, &C[c * 4 + eh], 8);
                __hip_atomic_store((u64*)&p[512 + l * 64 + c * 8 + 2 * eh], uv,
                                   __ATOMIC_RELAXED, __HIP_MEMORY_SCOPE_AGENT);
            }
        if (cb == 0) {
            float* o = out + n * SIGLEN;
            if (b == 0) o[a] = pbuf[2040 + a] - pbuf[a];
            float s2 = WSS[0][l];
            #pragma unroll
            for (int s = 1; s < 64; ++s) s2 += WSS[s][l];
            o[8 + l] = s2;
        }
        asm volatile("s_waitcnt vmcnt(0)" ::: "memory");
    }
    __syncthreads();
    if (t == 0)
        sh_old = __hip_atomic_fetch_add(&flags[n], 1, __ATOMIC_RELAXED,
                                        __HIP_MEMORY_SCOPE_AGENT);
    __syncthreads();
    if (sh_old != 7) return;          // not the last arriver

    // ---- combiner: flat 8-way sum of the partials -> out[72..4680) ----
    {
        float* o = out + n * SIGLEN;
        const u64* p0 = (const u64*)(pbase + (size_t)(n * 8) * PSTR);
        for (int i = t; i < PSTR / 2; i += 512) {
            v2f sum = (v2f)0.f;
            #pragma unroll
            for (int pi = 0; pi < 8; ++pi) {
                u64 uv = __hip_atomic_load(&p0[(size_t)pi * (PSTR / 2) + i],
                                           __ATOMIC_RELAXED,
                                           __HIP_MEMORY_SCOPE_AGENT);
                v2f v; __builtin_memcpy(&v, &uv, 8);
                sum += v;
            }
            *(v2f*)&o[72 + 2 * i] = sum;
        }
    }
}

extern "C" void kernel_launch(void* const* d_in, const int* in_sizes, int n_in,
                              void* d_out, int out_size, void* d_ws, size_t ws_size,
                              hipStream_t stream) {
    const float* path = (const float*)d_in[0];
    float* out = (float*)d_out;
    int* flags = (int*)d_ws;                      // 32 ints
    float* pbase = (float*)d_ws + 256;            // partials, 1 KB offset
    hipMemsetAsync(d_ws, 0, NBATCH * sizeof(int), stream);
    sig_kernel<<<NBATCH * 8, 512, 0, stream>>>(path, pbase, flags, out);
}